// Round 2
// baseline (506.162 us; speedup 1.0000x reference)
//
#include <hip/hip_runtime.h>
#include <math.h>

#define GLN_EPS 1e-6f
#define NW 16                   // waves per block -> 2 blocks/CU * 16 = 32 waves/CU
#define BLOCK (NW * 64)         // 1024 threads
#define CCH 256                 // channels (fixed by problem)
#define C4 (CCH / 4)            // 64 float4 per row == one wave
#define RCAP 2048               // rows of per-row-mean cache in LDS

typedef float v4f __attribute__((ext_vector_type(4)));

__device__ __forceinline__ void nt_store4(const float4& val, float4* p) {
    v4f t; t.x = val.x; t.y = val.y; t.z = val.z; t.w = val.w;
    __builtin_nontemporal_store(t, (v4f*)p);
}

__device__ __forceinline__ float wave_reduce_sum(float x) {
#pragma unroll
    for (int off = 32; off > 0; off >>= 1) x += __shfl_xor(x, off);
    return x;
}

__global__ void __launch_bounds__(BLOCK, 8) gln_kernel(
    const float* __restrict__ s, const float* __restrict__ v,
    const float* __restrict__ weight, const float* __restrict__ bias,
    const int* __restrict__ splits,
    float* __restrict__ sout, float* __restrict__ vout)
{
    __shared__ float4 csum_part[NW][C4];   // 16 KB
    __shared__ float4 mg4[C4];
    __shared__ float4 w4s[C4];
    __shared__ float4 b4s[C4];
    __shared__ float  rowmean_s[RCAP];     // 8 KB: per-row mean cache (pass A -> pass C)
    __shared__ float  red[NW][3];
    __shared__ int    ired[NW];
    __shared__ float  s_mg2;

    const int tid  = threadIdx.x;
    const int wv   = tid >> 6;
    const int lane = tid & 63;
    const int g    = blockIdx.x;

    // ---- start offset = prefix sum of splits[0..g) ----
    int acc = 0;
    for (int i = tid; i < g; i += BLOCK) acc += splits[i];
#pragma unroll
    for (int off = 32; off > 0; off >>= 1) acc += __shfl_xor(acc, off);
    if (lane == 0) ired[wv] = acc;
    if (wv == 0) {                       // cache weight/bias (wave 0)
        w4s[lane] = ((const float4*)weight)[lane];
        b4s[lane] = ((const float4*)bias)[lane];
    }
    __syncthreads();
    int start = 0;
#pragma unroll
    for (int i = 0; i < NW; i++) start += ired[i];
    const int cnt = splits[g];
    if (cnt <= 0) return;
    const float inv_cnt  = 1.0f / (float)cnt;
    const float inv_C    = 1.0f / (float)CCH;
    const float inv_cntC = inv_cnt * inv_C;

    const float4* s4p = (const float4*)s;
    const float4* v4p = (const float4*)v;

    // ---- pass A: accumulate stats ----
    float4 colsum = make_float4(0.f, 0.f, 0.f, 0.f);
    float sumsq = 0.f, rs2 = 0.f, vn = 0.f;

    for (int rr = wv; rr < cnt; rr += NW) {
        const size_t row = (size_t)(start + rr);
        float4 sv = s4p[row * C4 + lane];
        colsum.x += sv.x; colsum.y += sv.y; colsum.z += sv.z; colsum.w += sv.w;
        sumsq = fmaf(sv.x, sv.x, sumsq);
        sumsq = fmaf(sv.y, sv.y, sumsq);
        sumsq = fmaf(sv.z, sv.z, sumsq);
        sumsq = fmaf(sv.w, sv.w, sumsq);
        float rsum = wave_reduce_sum(sv.x + sv.y + sv.z + sv.w);
        if (lane == 0) {
            rs2 = fmaf(rsum, rsum, rs2);
            if (rr < RCAP) rowmean_s[rr] = rsum * inv_C;   // cache for pass C
        }

        const size_t vb = row * (3 * C4) + lane;
        float4 a  = v4p[vb];
        float4 bq = v4p[vb + C4];
        float4 cq = v4p[vb + 2 * C4];
        float nx = sqrtf(fmaf(a.x, a.x, fmaf(bq.x, bq.x, cq.x * cq.x)) + GLN_EPS);
        float ny = sqrtf(fmaf(a.y, a.y, fmaf(bq.y, bq.y, cq.y * cq.y)) + GLN_EPS);
        float nz = sqrtf(fmaf(a.z, a.z, fmaf(bq.z, bq.z, cq.z * cq.z)) + GLN_EPS);
        float nw = sqrtf(fmaf(a.w, a.w, fmaf(bq.w, bq.w, cq.w * cq.w)) + GLN_EPS);
        float vsum = wave_reduce_sum(nx + ny + nz + nw);
        if (lane == 0) vn += vsum;
    }
    csum_part[wv][lane] = colsum;

    // ---- block-reduce the three scalars ----
    float t0 = wave_reduce_sum(sumsq);
    float t1 = wave_reduce_sum(rs2);   // nonzero only on lane 0 pre-reduce
    float t2 = wave_reduce_sum(vn);
    if (lane == 0) { red[wv][0] = t0; red[wv][1] = t1; red[wv][2] = t2; }
    __syncthreads();
    float sumsq_tot = 0.f, rs2_tot = 0.f, vn_tot = 0.f;
#pragma unroll
    for (int i = 0; i < NW; i++) {
        sumsq_tot += red[i][0]; rs2_tot += red[i][1]; vn_tot += red[i][2];
    }

    // ---- wave 0: per-channel graph mean + its sum of squares ----
    if (wv == 0) {
        float4 t = csum_part[0][lane];
#pragma unroll
        for (int i = 1; i < NW; i++) {
            t.x += csum_part[i][lane].x; t.y += csum_part[i][lane].y;
            t.z += csum_part[i][lane].z; t.w += csum_part[i][lane].w;
        }
        float gsum  = wave_reduce_sum(t.x + t.y + t.z + t.w); // grand total of s
        float gmean = gsum * inv_cntC;                        // grand/(cnt*C)
        float4 mg;
        mg.x = t.x * inv_cnt - gmean;
        mg.y = t.y * inv_cnt - gmean;
        mg.z = t.z * inv_cnt - gmean;
        mg.w = t.w * inv_cnt - gmean;
        mg4[lane] = mg;
        float mg2 = wave_reduce_sum(mg.x * mg.x + mg.y * mg.y + mg.z * mg.z + mg.w * mg.w);
        if (lane == 0) s_mg2 = mg2;
    }
    __syncthreads();

    const float sum_mg2  = s_mg2;
    const float sum_s0sq = sumsq_tot - rs2_tot * inv_C;
    const float sum_cs2  = sum_s0sq - (float)cnt * sum_mg2;
    const float var      = sum_cs2 * inv_cntC;
    const float rstd     = 1.0f / sqrtf(var + GLN_EPS);
    const float vnorm_g  = vn_tot * inv_cntC;
    const float rvn      = 1.0f / vnorm_g;

    // ---- pass C: produce outputs (pure stream: load -> fma -> nt-store) ----
    float4 wl = w4s[lane];
    wl.x *= rstd; wl.y *= rstd; wl.z *= rstd; wl.w *= rstd;
    const float4 bl = b4s[lane];
    const float4 mg = mg4[lane];
    float4* so4 = (float4*)sout;
    float4* vo4 = (float4*)vout;

    for (int rr = wv; rr < cnt; rr += NW) {
        const size_t row = (size_t)(start + rr);
        float4 sv = s4p[row * C4 + lane];
        float rmean;
        if (rr < RCAP) {
            rmean = rowmean_s[rr];                     // LDS broadcast, no shuffle chain
        } else {
            rmean = wave_reduce_sum(sv.x + sv.y + sv.z + sv.w) * inv_C;
        }
        float4 o;
        o.x = fmaf(sv.x - rmean - mg.x, wl.x, bl.x);
        o.y = fmaf(sv.y - rmean - mg.y, wl.y, bl.y);
        o.z = fmaf(sv.z - rmean - mg.z, wl.z, bl.z);
        o.w = fmaf(sv.w - rmean - mg.w, wl.w, bl.w);
        nt_store4(o, &so4[row * C4 + lane]);

        const size_t vb = row * (3 * C4) + lane;
        float4 a  = v4p[vb];
        float4 bq = v4p[vb + C4];
        float4 cq = v4p[vb + 2 * C4];
        a.x  *= rvn; a.y  *= rvn; a.z  *= rvn; a.w  *= rvn;
        bq.x *= rvn; bq.y *= rvn; bq.z *= rvn; bq.w *= rvn;
        cq.x *= rvn; cq.y *= rvn; cq.z *= rvn; cq.w *= rvn;
        nt_store4(a,  &vo4[vb]);
        nt_store4(bq, &vo4[vb + C4]);
        nt_store4(cq, &vo4[vb + 2 * C4]);
    }
}

extern "C" void kernel_launch(void* const* d_in, const int* in_sizes, int n_in,
                              void* d_out, int out_size, void* d_ws, size_t ws_size,
                              hipStream_t stream) {
    const float* s      = (const float*)d_in[0];
    const float* v      = (const float*)d_in[1];
    const float* w      = (const float*)d_in[2];
    const float* b      = (const float*)d_in[3];
    const int*   splits = (const int*)d_in[4];
    const int N = in_sizes[0] / CCH;
    const int G = in_sizes[4];
    float* out  = (float*)d_out;
    float* sout = out;
    float* vout = out + (size_t)N * CCH;
    gln_kernel<<<G, BLOCK, 0, stream>>>(s, v, w, b, splits, sout, vout);
}

// Round 3
// 482.957 us; speedup vs baseline: 1.0480x; 1.0480x over previous
//
#include <hip/hip_runtime.h>
#include <math.h>

#define GLN_EPS 1e-6f
#define NW 8                    // waves per block (512 threads; round-2 showed 16-wave blocks gain nothing)
#define BLOCK (NW * 64)
#define CCH 256                 // channels (fixed by problem)
#define C4 (CCH / 4)            // 64 float4 per row == one wave
#define RCAP 2048               // rows of per-row-mean cache in LDS (fallback path)
#define RMAX 16                 // specialized path: rows per wave when cnt == NW*RMAX (= 128)

__device__ __forceinline__ float wave_reduce_sum(float x) {
#pragma unroll
    for (int off = 32; off > 0; off >>= 1) x += __shfl_xor(x, off);
    return x;
}

__global__ void __launch_bounds__(BLOCK, 4) gln_kernel(
    const float* __restrict__ s, const float* __restrict__ v,
    const float* __restrict__ weight, const float* __restrict__ bias,
    const int* __restrict__ splits,
    float* __restrict__ sout, float* __restrict__ vout)
{
    __shared__ float4 csum_part[NW][C4];   // 8 KB
    __shared__ float4 mg4[C4];
    __shared__ float4 w4s[C4];
    __shared__ float4 b4s[C4];
    __shared__ float  rowmean_s[RCAP];     // 8 KB: per-row mean, pass A -> pass C
    __shared__ float  red[NW][3];
    __shared__ int    ired[NW];
    __shared__ float  s_mg2;

    const int tid  = threadIdx.x;
    const int wv   = tid >> 6;
    const int lane = tid & 63;
    const int g    = blockIdx.x;

    // ---- start offset = prefix sum of splits[0..g) ----
    int acc = 0;
    for (int i = tid; i < g; i += BLOCK) acc += splits[i];
#pragma unroll
    for (int off = 32; off > 0; off >>= 1) acc += __shfl_xor(acc, off);
    if (lane == 0) ired[wv] = acc;
    if (wv == 0) {                       // cache weight/bias (wave 0)
        w4s[lane] = ((const float4*)weight)[lane];
        b4s[lane] = ((const float4*)bias)[lane];
    }
    __syncthreads();
    int start = 0;
#pragma unroll
    for (int i = 0; i < NW; i++) start += ired[i];
    const int cnt = splits[g];
    if (cnt <= 0) return;
    const float inv_cnt  = 1.0f / (float)cnt;
    const float inv_C    = 1.0f / (float)CCH;
    const float inv_cntC = inv_cnt * inv_C;

    const float4* s4p = (const float4*)s;
    const float4* v4p = (const float4*)v;

    const bool fast = (cnt == NW * RMAX);

    // ---- pass A: accumulate stats ----
    float4 colsum = make_float4(0.f, 0.f, 0.f, 0.f);
    float sumsq = 0.f, rs2 = 0.f, vn = 0.f;
    float4 svs[RMAX];                      // s rows persisted across the barrier (fast path)

    if (fast) {
        // s: load all 16 rows up front (64 VGPRs), stats fully pipelined
#pragma unroll
        for (int k = 0; k < RMAX; k++) {
            const size_t row = (size_t)(start + wv + k * NW);
            svs[k] = s4p[row * C4 + lane];
        }
#pragma unroll
        for (int k = 0; k < RMAX; k++) {
            const float4 sv = svs[k];
            colsum.x += sv.x; colsum.y += sv.y; colsum.z += sv.z; colsum.w += sv.w;
            sumsq = fmaf(sv.x, sv.x, sumsq);
            sumsq = fmaf(sv.y, sv.y, sumsq);
            sumsq = fmaf(sv.z, sv.z, sumsq);
            sumsq = fmaf(sv.w, sv.w, sumsq);
            float rsum = wave_reduce_sum(sv.x + sv.y + sv.z + sv.w);
            if (lane == 0) {
                rs2 = fmaf(rsum, rsum, rs2);
                rowmean_s[wv + k * NW] = rsum * inv_C;
            }
        }
        // v: pure lane-local streaming reduce (vn_tot is a flat sum: NO per-row reduce needed)
#pragma unroll 4
        for (int k = 0; k < RMAX; k++) {
            const size_t row = (size_t)(start + wv + k * NW);
            const size_t vb  = row * (3 * C4) + lane;
            float4 a  = v4p[vb];
            float4 bq = v4p[vb + C4];
            float4 cq = v4p[vb + 2 * C4];
            vn += sqrtf(fmaf(a.x, a.x, fmaf(bq.x, bq.x, cq.x * cq.x)) + GLN_EPS);
            vn += sqrtf(fmaf(a.y, a.y, fmaf(bq.y, bq.y, cq.y * cq.y)) + GLN_EPS);
            vn += sqrtf(fmaf(a.z, a.z, fmaf(bq.z, bq.z, cq.z * cq.z)) + GLN_EPS);
            vn += sqrtf(fmaf(a.w, a.w, fmaf(bq.w, bq.w, cq.w * cq.w)) + GLN_EPS);
        }
    } else {
        for (int rr = wv; rr < cnt; rr += NW) {
            const size_t row = (size_t)(start + rr);
            float4 sv = s4p[row * C4 + lane];
            colsum.x += sv.x; colsum.y += sv.y; colsum.z += sv.z; colsum.w += sv.w;
            sumsq = fmaf(sv.x, sv.x, sumsq);
            sumsq = fmaf(sv.y, sv.y, sumsq);
            sumsq = fmaf(sv.z, sv.z, sumsq);
            sumsq = fmaf(sv.w, sv.w, sumsq);
            float rsum = wave_reduce_sum(sv.x + sv.y + sv.z + sv.w);
            if (lane == 0) {
                rs2 = fmaf(rsum, rsum, rs2);
                if (rr < RCAP) rowmean_s[rr] = rsum * inv_C;
            }
            const size_t vb = row * (3 * C4) + lane;
            float4 a  = v4p[vb];
            float4 bq = v4p[vb + C4];
            float4 cq = v4p[vb + 2 * C4];
            vn += sqrtf(fmaf(a.x, a.x, fmaf(bq.x, bq.x, cq.x * cq.x)) + GLN_EPS);
            vn += sqrtf(fmaf(a.y, a.y, fmaf(bq.y, bq.y, cq.y * cq.y)) + GLN_EPS);
            vn += sqrtf(fmaf(a.z, a.z, fmaf(bq.z, bq.z, cq.z * cq.z)) + GLN_EPS);
            vn += sqrtf(fmaf(a.w, a.w, fmaf(bq.w, bq.w, cq.w * cq.w)) + GLN_EPS);
        }
    }
    csum_part[wv][lane] = colsum;

    // ---- block-reduce the three scalars ----
    float t0 = wave_reduce_sum(sumsq);
    float t1 = wave_reduce_sum(rs2);   // nonzero only on lane 0 pre-reduce
    float t2 = wave_reduce_sum(vn);
    if (lane == 0) { red[wv][0] = t0; red[wv][1] = t1; red[wv][2] = t2; }
    __syncthreads();
    float sumsq_tot = 0.f, rs2_tot = 0.f, vn_tot = 0.f;
#pragma unroll
    for (int i = 0; i < NW; i++) {
        sumsq_tot += red[i][0]; rs2_tot += red[i][1]; vn_tot += red[i][2];
    }

    // ---- wave 0: per-channel graph mean + its sum of squares ----
    if (wv == 0) {
        float4 t = csum_part[0][lane];
#pragma unroll
        for (int i = 1; i < NW; i++) {
            t.x += csum_part[i][lane].x; t.y += csum_part[i][lane].y;
            t.z += csum_part[i][lane].z; t.w += csum_part[i][lane].w;
        }
        float gsum  = wave_reduce_sum(t.x + t.y + t.z + t.w); // grand total of s
        float gmean = gsum * inv_cntC;                        // grand/(cnt*C)
        float4 mg;
        mg.x = t.x * inv_cnt - gmean;
        mg.y = t.y * inv_cnt - gmean;
        mg.z = t.z * inv_cnt - gmean;
        mg.w = t.w * inv_cnt - gmean;
        mg4[lane] = mg;
        float mg2 = wave_reduce_sum(mg.x * mg.x + mg.y * mg.y + mg.z * mg.z + mg.w * mg.w);
        if (lane == 0) s_mg2 = mg2;
    }
    __syncthreads();

    const float sum_mg2  = s_mg2;
    const float sum_s0sq = sumsq_tot - rs2_tot * inv_C;
    const float sum_cs2  = sum_s0sq - (float)cnt * sum_mg2;
    const float var      = sum_cs2 * inv_cntC;
    const float rstd     = 1.0f / sqrtf(var + GLN_EPS);
    const float vnorm_g  = vn_tot * inv_cntC;
    const float rvn      = 1.0f / vnorm_g;

    // ---- pass C: produce outputs ----
    float4 wl = w4s[lane];
    wl.x *= rstd; wl.y *= rstd; wl.z *= rstd; wl.w *= rstd;
    const float4 bl = b4s[lane];
    const float4 mg = mg4[lane];
    float4* so4 = (float4*)sout;
    float4* vo4 = (float4*)vout;

    if (fast) {
        // s outputs straight from registers: all 16 stores issue immediately,
        // overlapping the write stream with the v-load stream below.
#pragma unroll
        for (int k = 0; k < RMAX; k++) {
            const size_t row = (size_t)(start + wv + k * NW);
            const float rmean = rowmean_s[wv + k * NW];   // LDS broadcast
            const float4 sv = svs[k];
            float4 o;
            o.x = fmaf(sv.x - rmean - mg.x, wl.x, bl.x);
            o.y = fmaf(sv.y - rmean - mg.y, wl.y, bl.y);
            o.z = fmaf(sv.z - rmean - mg.z, wl.z, bl.z);
            o.w = fmaf(sv.w - rmean - mg.w, wl.w, bl.w);
            so4[row * C4 + lane] = o;
        }
#pragma unroll 2
        for (int k = 0; k < RMAX; k++) {
            const size_t row = (size_t)(start + wv + k * NW);
            const size_t vb  = row * (3 * C4) + lane;
            float4 a  = v4p[vb];
            float4 bq = v4p[vb + C4];
            float4 cq = v4p[vb + 2 * C4];
            a.x  *= rvn; a.y  *= rvn; a.z  *= rvn; a.w  *= rvn;
            bq.x *= rvn; bq.y *= rvn; bq.z *= rvn; bq.w *= rvn;
            cq.x *= rvn; cq.y *= rvn; cq.z *= rvn; cq.w *= rvn;
            vo4[vb]          = a;
            vo4[vb + C4]     = bq;
            vo4[vb + 2 * C4] = cq;
        }
    } else {
        for (int rr = wv; rr < cnt; rr += NW) {
            const size_t row = (size_t)(start + rr);
            float4 sv = s4p[row * C4 + lane];
            float rmean;
            if (rr < RCAP) {
                rmean = rowmean_s[rr];
            } else {
                rmean = wave_reduce_sum(sv.x + sv.y + sv.z + sv.w) * inv_C;
            }
            float4 o;
            o.x = fmaf(sv.x - rmean - mg.x, wl.x, bl.x);
            o.y = fmaf(sv.y - rmean - mg.y, wl.y, bl.y);
            o.z = fmaf(sv.z - rmean - mg.z, wl.z, bl.z);
            o.w = fmaf(sv.w - rmean - mg.w, wl.w, bl.w);
            so4[row * C4 + lane] = o;

            const size_t vb = row * (3 * C4) + lane;
            float4 a  = v4p[vb];
            float4 bq = v4p[vb + C4];
            float4 cq = v4p[vb + 2 * C4];
            a.x  *= rvn; a.y  *= rvn; a.z  *= rvn; a.w  *= rvn;
            bq.x *= rvn; bq.y *= rvn; bq.z *= rvn; bq.w *= rvn;
            cq.x *= rvn; cq.y *= rvn; cq.z *= rvn; cq.w *= rvn;
            vo4[vb]          = a;
            vo4[vb + C4]     = bq;
            vo4[vb + 2 * C4] = cq;
        }
    }
}

extern "C" void kernel_launch(void* const* d_in, const int* in_sizes, int n_in,
                              void* d_out, int out_size, void* d_ws, size_t ws_size,
                              hipStream_t stream) {
    const float* s      = (const float*)d_in[0];
    const float* v      = (const float*)d_in[1];
    const float* w      = (const float*)d_in[2];
    const float* b      = (const float*)d_in[3];
    const int*   splits = (const int*)d_in[4];
    const int N = in_sizes[0] / CCH;
    const int G = in_sizes[4];
    float* out  = (float*)d_out;
    float* sout = out;
    float* vout = out + (size_t)N * CCH;
    gln_kernel<<<G, BLOCK, 0, stream>>>(s, v, w, b, splits, sout, vout);
}